// Round 1
// baseline (1747.926 us; speedup 1.0000x reference)
//
#include <hip/hip_runtime.h>

namespace {

constexpr int kE  = 1024;
constexpr int kH  = 16;
constexpr int kR  = 256;
constexpr int kHD = 64;
constexpr int kB  = 2;
constexpr int kS  = 2048;
constexpr int kM  = kB * kS;   // 4096 rows in all projection GEMMs

// ---------------------------------------------------------------------------
// C[M,N] = A[M,K] @ B[K,N] + bias[N]   (fp32, all dims multiples of 64/16)
// 64x64 block tile, BK=16, 256 threads, 4x4 micro-tile per thread.
// ---------------------------------------------------------------------------
__global__ __launch_bounds__(256) void gemm_bias(
    const float* __restrict__ A, const float* __restrict__ Bm,
    const float* __restrict__ bias, float* __restrict__ C,
    int M, int N, int K)
{
  // +4 pad: keeps rows 16B-aligned for wide LDS ops, breaks pow-2 bank strides
  __shared__ float As[16][68];   // As[k][m]
  __shared__ float Bs[16][68];   // Bs[k][n]

  const int t  = threadIdx.x;
  const int tx = t & 15;
  const int ty = t >> 4;
  const int row0 = blockIdx.y * 64;
  const int col0 = blockIdx.x * 64;

  // A-tile load: thread t loads float4 at A[row0 + t/4][kk + (t%4)*4]
  const int arow = t >> 2;
  const int acol = (t & 3) * 4;
  // B-tile load: thread t loads float4 at B[kk + t/16][col0 + (t%16)*4]
  const int brow = t >> 4;
  const int bcol = (t & 15) * 4;

  float acc[4][4] = {};

  for (int kk = 0; kk < K; kk += 16) {
    float4 av = *(const float4*)&A[(size_t)(row0 + arow) * K + kk + acol];
    float4 bv = *(const float4*)&Bm[(size_t)(kk + brow) * N + col0 + bcol];
    As[acol + 0][arow] = av.x;
    As[acol + 1][arow] = av.y;
    As[acol + 2][arow] = av.z;
    As[acol + 3][arow] = av.w;
    *(float4*)&Bs[brow][bcol] = bv;
    __syncthreads();

#pragma unroll
    for (int k = 0; k < 16; ++k) {
      float a[4], b[4];
#pragma unroll
      for (int i = 0; i < 4; ++i) a[i] = As[k][ty * 4 + i];
#pragma unroll
      for (int j = 0; j < 4; ++j) b[j] = Bs[k][tx * 4 + j];
#pragma unroll
      for (int i = 0; i < 4; ++i)
#pragma unroll
        for (int j = 0; j < 4; ++j) acc[i][j] += a[i] * b[j];
    }
    __syncthreads();
  }

#pragma unroll
  for (int i = 0; i < 4; ++i) {
    const int r = row0 + ty * 4 + i;
#pragma unroll
    for (int j = 0; j < 4; ++j) {
      const int c = col0 + tx * 4 + j;
      C[(size_t)r * N + c] = acc[i][j] + bias[c];
    }
  }
}

// ---------------------------------------------------------------------------
// Flash-style attention, fp32. One 64-lane wave per block; each lane owns one
// Q row (q and O accumulator in registers). K/V staged in LDS in chunks of 16;
// LDS reads in the dot/accum loops are same-address across lanes (broadcast,
// conflict-free). Online softmax with running (m, l).
// Q/K/V/O all stored as (B, S, E) with head h occupying columns [h*64, h*64+64).
// ---------------------------------------------------------------------------
__global__ __launch_bounds__(64) void attn_kernel(
    const float* __restrict__ Q, const float* __restrict__ K,
    const float* __restrict__ V, float* __restrict__ O)
{
  constexpr int KC = 16;
  __shared__ float Ks[KC][kHD];
  __shared__ float Vs[KC][kHD];

  const int lane = threadIdx.x;           // 0..63
  const int qrow = blockIdx.x * 64 + lane;
  const int bh   = blockIdx.y;
  const int b    = bh / kH;
  const int h    = bh % kH;
  const size_t base = (size_t)b * kS * kE + (size_t)h * kHD;  // +s*kE+d

  const float scale = 0.125f;             // 1/sqrt(HD)

  float q[kHD];
#pragma unroll
  for (int d = 0; d < kHD; ++d)
    q[d] = Q[base + (size_t)qrow * kE + d] * scale;

  float o[kHD] = {};
  float m = -1e30f;
  float l = 0.f;

  for (int kt = 0; kt < kS; kt += KC) {
    __syncthreads();
    // cooperative load: lane d loads column d of each of the KC rows (coalesced)
    for (int r = 0; r < KC; ++r) {
      Ks[r][lane] = K[base + (size_t)(kt + r) * kE + lane];
      Vs[r][lane] = V[base + (size_t)(kt + r) * kE + lane];
    }
    __syncthreads();

    float sl[KC];
    float mnew = m;
    for (int r = 0; r < KC; ++r) {
      float s = 0.f;
#pragma unroll
      for (int d = 0; d < kHD; ++d) s += q[d] * Ks[r][d];
      sl[r] = s;
      mnew = fmaxf(mnew, s);
    }

    const float alpha = __expf(m - mnew);
    m = mnew;
    l *= alpha;
#pragma unroll
    for (int d = 0; d < kHD; ++d) o[d] *= alpha;

    for (int r = 0; r < KC; ++r) {
      const float p = __expf(sl[r] - m);
      l += p;
#pragma unroll
      for (int d = 0; d < kHD; ++d) o[d] += p * Vs[r][d];
    }
  }

  const float inv = 1.f / l;
#pragma unroll
  for (int d = 0; d < kHD; ++d)
    O[base + (size_t)qrow * kE + d] = o[d] * inv;
}

}  // namespace

// ---------------------------------------------------------------------------
// Input order (setup_inputs): query, key, value, then per {q,k,v,o}:
// W_lo (E,R), b_lo (R), W_hi (R,E), b_hi (E). All fp32.
// ---------------------------------------------------------------------------
extern "C" void kernel_launch(void* const* d_in, const int* in_sizes, int n_in,
                              void* d_out, int out_size, void* d_ws, size_t ws_size,
                              hipStream_t stream) {
  const float* query = (const float*)d_in[0];
  const float* key_  = (const float*)d_in[1];
  const float* value = (const float*)d_in[2];

  float* ws = (float*)d_ws;
  float* Qb = ws;                     // 4096*1024
  float* Kb = Qb + (size_t)kM * kE;   // 4096*1024
  float* Vb = Kb + (size_t)kM * kE;   // 4096*1024
  float* Ab = Vb + (size_t)kM * kE;   // 4096*1024 (attention out)
  float* Tb = Ab + (size_t)kM * kE;   // 4096*256  (low-rank intermediate)

  const dim3 blk(256);
  const dim3 grid_lo(kR / 64, kM / 64);   // N=256
  const dim3 grid_hi(kE / 64, kM / 64);   // N=1024

  auto lowrank = [&](const float* X, int wbase, float* out) {
    const float* Wlo = (const float*)d_in[wbase + 0];
    const float* blo = (const float*)d_in[wbase + 1];
    const float* Whi = (const float*)d_in[wbase + 2];
    const float* bhi = (const float*)d_in[wbase + 3];
    gemm_bias<<<grid_lo, blk, 0, stream>>>(X,  Wlo, blo, Tb,  kM, kR, kE);
    gemm_bias<<<grid_hi, blk, 0, stream>>>(Tb, Whi, bhi, out, kM, kE, kR);
  };

  lowrank(query, 3,  Qb);
  lowrank(key_,  7,  Kb);
  lowrank(value, 11, Vb);

  attn_kernel<<<dim3(kS / 64, kB * kH), dim3(64), 0, stream>>>(Qb, Kb, Vb, Ab);

  // output projection -> d_out
  {
    const float* Wlo = (const float*)d_in[15];
    const float* blo = (const float*)d_in[16];
    const float* Whi = (const float*)d_in[17];
    const float* bhi = (const float*)d_in[18];
    gemm_bias<<<grid_lo, blk, 0, stream>>>(Ab, Wlo, blo, Tb, kM, kR, kE);
    gemm_bias<<<grid_hi, blk, 0, stream>>>(Tb, Whi, bhi, (float*)d_out, kM, kE, kR);
  }
}

// Round 2
// 764.030 us; speedup vs baseline: 2.2878x; 2.2878x over previous
//
#include <hip/hip_runtime.h>

namespace {

constexpr int kE  = 1024;
constexpr int kH  = 16;
constexpr int kR  = 256;
constexpr int kHD = 64;
constexpr int kB  = 2;
constexpr int kS  = 2048;
constexpr int kM  = kB * kS;   // 4096 rows in all projection GEMMs

typedef float  floatx4 __attribute__((ext_vector_type(4)));
typedef short  short8  __attribute__((ext_vector_type(8)));
typedef short  short4  __attribute__((ext_vector_type(4)));

__device__ inline short f2bf(float f) {
  union { float f; unsigned u; } x{f};
  unsigned r = x.u + 0x7FFF + ((x.u >> 16) & 1);   // RNE
  return (short)(r >> 16);
}

// ---------------------------------------------------------------------------
// C[M,N] = A[M,K] @ B[K,N] + bias[N]   (fp32)  -- unchanged from round 0
// ---------------------------------------------------------------------------
__global__ __launch_bounds__(256) void gemm_bias(
    const float* __restrict__ A, const float* __restrict__ Bm,
    const float* __restrict__ bias, float* __restrict__ C,
    int M, int N, int K)
{
  __shared__ float As[16][68];
  __shared__ float Bs[16][68];

  const int t  = threadIdx.x;
  const int tx = t & 15;
  const int ty = t >> 4;
  const int row0 = blockIdx.y * 64;
  const int col0 = blockIdx.x * 64;

  const int arow = t >> 2;
  const int acol = (t & 3) * 4;
  const int brow = t >> 4;
  const int bcol = (t & 15) * 4;

  float acc[4][4] = {};

  for (int kk = 0; kk < K; kk += 16) {
    float4 av = *(const float4*)&A[(size_t)(row0 + arow) * K + kk + acol];
    float4 bv = *(const float4*)&Bm[(size_t)(kk + brow) * N + col0 + bcol];
    As[acol + 0][arow] = av.x;
    As[acol + 1][arow] = av.y;
    As[acol + 2][arow] = av.z;
    As[acol + 3][arow] = av.w;
    *(float4*)&Bs[brow][bcol] = bv;
    __syncthreads();

#pragma unroll
    for (int k = 0; k < 16; ++k) {
      float a[4], b[4];
#pragma unroll
      for (int i = 0; i < 4; ++i) a[i] = As[k][ty * 4 + i];
#pragma unroll
      for (int j = 0; j < 4; ++j) b[j] = Bs[k][tx * 4 + j];
#pragma unroll
      for (int i = 0; i < 4; ++i)
#pragma unroll
        for (int j = 0; j < 4; ++j) acc[i][j] += a[i] * b[j];
    }
    __syncthreads();
  }

#pragma unroll
  for (int i = 0; i < 4; ++i) {
    const int r = row0 + ty * 4 + i;
#pragma unroll
    for (int j = 0; j < 4; ++j) {
      const int c = col0 + tx * 4 + j;
      C[(size_t)r * N + c] = acc[i][j] + bias[c];
    }
  }
}

// ---------------------------------------------------------------------------
// fp32 -> bf16 convert for Q (scaled by 1/8) and K.  4 floats / thread.
// ---------------------------------------------------------------------------
__global__ __launch_bounds__(256) void convert_qk(
    const float* __restrict__ Q, const float* __restrict__ K,
    short* __restrict__ Qh, short* __restrict__ Kh)
{
  const size_t i = ((size_t)blockIdx.x * 256 + threadIdx.x) * 4;
  float4 q = *(const float4*)(Q + i);
  float4 k = *(const float4*)(K + i);
  short4 qo = { f2bf(q.x * 0.125f), f2bf(q.y * 0.125f),
                f2bf(q.z * 0.125f), f2bf(q.w * 0.125f) };
  short4 ko = { f2bf(k.x), f2bf(k.y), f2bf(k.z), f2bf(k.w) };
  *(short4*)(Qh + i) = qo;
  *(short4*)(Kh + i) = ko;
}

// ---------------------------------------------------------------------------
// V (B,S,E) fp32  ->  Vt (B*H, 64, S) bf16  (per-head transpose)
// Block: one (b,h) x 64-s tile. LDS tile transpose, pad 68 keeps 16B align.
// ---------------------------------------------------------------------------
__global__ __launch_bounds__(256) void transpose_v(
    const float* __restrict__ V, short* __restrict__ Vt)
{
  __shared__ float tile[64][68];
  const int bh = blockIdx.y;
  const int b  = bh >> 4;
  const int h  = bh & 15;
  const int s0 = blockIdx.x * 64;
  const int t  = threadIdx.x;
  const int c4 = (t & 15) * 4;
  const int r  = t >> 4;

#pragma unroll
  for (int i = 0; i < 4; ++i) {
    const int row = r + i * 16;
    float4 v = *(const float4*)&V[((size_t)(b * kS + s0 + row)) * kE + h * kHD + c4];
    *(float4*)&tile[row][c4] = v;
  }
  __syncthreads();
#pragma unroll
  for (int i = 0; i < 4; ++i) {
    const int d = r + i * 16;
    short4 o = { f2bf(tile[c4 + 0][d]), f2bf(tile[c4 + 1][d]),
                 f2bf(tile[c4 + 2][d]), f2bf(tile[c4 + 3][d]) };
    *(short4*)&Vt[((size_t)bh * kHD + d) * kS + s0 + c4] = o;
  }
}

// ---------------------------------------------------------------------------
// Flash attention, bf16 MFMA. Block = 4 waves, each wave owns 16 q-rows.
// S^T = K @ Q^T  (A = K from global, B = Q^T in regs)
// O^T = V^T @ P^T (A = V^T from global Vt, B = P^T from wave-private LDS)
// No __syncthreads anywhere (P buffers are wave-private).
// ---------------------------------------------------------------------------
__global__ __launch_bounds__(256) void attn_mfma(
    const short* __restrict__ Qh, const short* __restrict__ Kh,
    const short* __restrict__ Vt, float* __restrict__ O)
{
  __shared__ short Pbuf_all[4][16][72];   // [wave][q][key] bf16, pad 72

  const int lane = threadIdx.x & 63;
  const int wave = threadIdx.x >> 6;
  const int lq   = lane & 15;     // n index (q) / m index (key or d)
  const int quad = lane >> 4;     // 0..3

  const int bh = blockIdx.y;
  const int b  = bh >> 4;
  const int h  = bh & 15;
  const int q0 = blockIdx.x * 64 + wave * 16;

  short (*Pbuf)[72] = Pbuf_all[wave];

  // Q^T B-fragments (held in regs whole kernel): n=q=lq, k=d
  const short* qrow = Qh + ((size_t)(b * kS + q0 + lq)) * kE + h * kHD;
  short8 qf0 = *(const short8*)(qrow + quad * 8);
  short8 qf1 = *(const short8*)(qrow + 32 + quad * 8);

  const short* Kbase = Kh + (size_t)b * kS * kE + h * kHD;
  const short* Vbase = Vt + (size_t)bh * kHD * kS;

  floatx4 Oacc[4] = {};
  float m = -1e30f;
  float l = 0.f;

  for (int kc = 0; kc < kS; kc += 64) {
    // ---- scores: S^T tiles (key16 x q16), contraction over d=64 ----
    floatx4 Sc[4];
#pragma unroll
    for (int t = 0; t < 4; ++t) {
      const short* krow = Kbase + ((size_t)(kc + t * 16 + lq)) * kE;
      short8 a0 = *(const short8*)(krow + quad * 8);
      short8 a1 = *(const short8*)(krow + 32 + quad * 8);
      floatx4 c = {};
      c = __builtin_amdgcn_mfma_f32_16x16x32_bf16(a0, qf0, c, 0, 0, 0);
      c = __builtin_amdgcn_mfma_f32_16x16x32_bf16(a1, qf1, c, 0, 0, 0);
      Sc[t] = c;
    }

    // ---- prefetch V^T A-fragments (independent of softmax) ----
    short8 vf[4][2];
#pragma unroll
    for (int dt = 0; dt < 4; ++dt) {
      const short* vrow = Vbase + ((size_t)(dt * 16 + lq)) * kS + kc;
      vf[dt][0] = *(const short8*)(vrow + quad * 8);
      vf[dt][1] = *(const short8*)(vrow + 32 + quad * 8);
    }

    // ---- online softmax ----
    float mc = -1e30f;
#pragma unroll
    for (int t = 0; t < 4; ++t)
#pragma unroll
      for (int r = 0; r < 4; ++r) mc = fmaxf(mc, Sc[t][r]);
    mc = fmaxf(mc, __shfl_xor(mc, 16, 64));
    mc = fmaxf(mc, __shfl_xor(mc, 32, 64));
    const float mn = fmaxf(m, mc);
    const float alpha = __expf(m - mn);
    m = mn;

    float ls = 0.f;
#pragma unroll
    for (int t = 0; t < 4; ++t) {
      float p0 = __expf(Sc[t][0] - m);
      float p1 = __expf(Sc[t][1] - m);
      float p2 = __expf(Sc[t][2] - m);
      float p3 = __expf(Sc[t][3] - m);
      ls += (p0 + p1) + (p2 + p3);
      short4 pk = { f2bf(p0), f2bf(p1), f2bf(p2), f2bf(p3) };
      // P[q=lq][key = t*16 + quad*4 + r]
      *(short4*)&Pbuf[lq][t * 16 + quad * 4] = pk;
    }
    l = l * alpha + ls;
#pragma unroll
    for (int dt = 0; dt < 4; ++dt)
#pragma unroll
      for (int r = 0; r < 4; ++r) Oacc[dt][r] *= alpha;

    // same-wave LDS RAW: force writes drained, stop compiler reordering
    asm volatile("s_waitcnt lgkmcnt(0)" ::: "memory");

    // ---- PV: O^T += V^T @ P^T ----
    short8 pb0 = *(const short8*)&Pbuf[lq][quad * 8];
    short8 pb1 = *(const short8*)&Pbuf[lq][32 + quad * 8];
#pragma unroll
    for (int dt = 0; dt < 4; ++dt) {
      Oacc[dt] = __builtin_amdgcn_mfma_f32_16x16x32_bf16(vf[dt][0], pb0, Oacc[dt], 0, 0, 0);
      Oacc[dt] = __builtin_amdgcn_mfma_f32_16x16x32_bf16(vf[dt][1], pb1, Oacc[dt], 0, 0, 0);
    }
    asm volatile("s_waitcnt lgkmcnt(0)" ::: "memory");  // reads done before next chunk's writes
  }

  // ---- epilogue ----
  l += __shfl_xor(l, 16, 64);
  l += __shfl_xor(l, 32, 64);
  const float inv = 1.f / l;

  float* orow = O + ((size_t)(b * kS + q0 + lq)) * kE + h * kHD;
#pragma unroll
  for (int dt = 0; dt < 4; ++dt) {
    float4 v;
    v.x = Oacc[dt][0] * inv;
    v.y = Oacc[dt][1] * inv;
    v.z = Oacc[dt][2] * inv;
    v.w = Oacc[dt][3] * inv;
    *(float4*)&orow[dt * 16 + quad * 4] = v;
  }
}

}  // namespace

extern "C" void kernel_launch(void* const* d_in, const int* in_sizes, int n_in,
                              void* d_out, int out_size, void* d_ws, size_t ws_size,
                              hipStream_t stream) {
  const float* query = (const float*)d_in[0];
  const float* key_  = (const float*)d_in[1];
  const float* value = (const float*)d_in[2];

  float* ws = (float*)d_ws;
  float* Qb = ws;                     // 4096*1024 f32
  float* Kb = Qb + (size_t)kM * kE;
  float* Vb = Kb + (size_t)kM * kE;
  float* Ab = Vb + (size_t)kM * kE;   // attention out f32
  float* Tb = Ab + (size_t)kM * kE;   // 4096*256 f32
  short* Qh = (short*)(Tb + (size_t)kM * kR);   // bf16 buffers
  short* Kh = Qh + (size_t)kM * kE;
  short* Vth = Kh + (size_t)kM * kE;            // (B*H, 64, S)

  const dim3 blk(256);
  const dim3 grid_lo(kR / 64, kM / 64);
  const dim3 grid_hi(kE / 64, kM / 64);

  auto lowrank = [&](const float* X, int wbase, float* out) {
    const float* Wlo = (const float*)d_in[wbase + 0];
    const float* blo = (const float*)d_in[wbase + 1];
    const float* Whi = (const float*)d_in[wbase + 2];
    const float* bhi = (const float*)d_in[wbase + 3];
    gemm_bias<<<grid_lo, blk, 0, stream>>>(X,  Wlo, blo, Tb,  kM, kR, kE);
    gemm_bias<<<grid_hi, blk, 0, stream>>>(Tb, Whi, bhi, out, kM, kE, kR);
  };

  lowrank(query, 3,  Qb);
  lowrank(key_,  7,  Kb);
  lowrank(value, 11, Vb);

  convert_qk<<<dim3((kM * kE) / (256 * 4)), blk, 0, stream>>>(Qb, Kb, Qh, Kh);
  transpose_v<<<dim3(kS / 64, kB * kH), blk, 0, stream>>>(Vb, Vth);

  attn_mfma<<<dim3(kS / 64, kB * kH), blk, 0, stream>>>(Qh, Kh, Vth, Ab);

  {
    const float* Wlo = (const float*)d_in[15];
    const float* blo = (const float*)d_in[16];
    const float* Whi = (const float*)d_in[17];
    const float* bhi = (const float*)d_in[18];
    gemm_bias<<<grid_lo, blk, 0, stream>>>(Ab, Wlo, blo, Tb, kM, kR, kE);
    gemm_bias<<<grid_hi, blk, 0, stream>>>(Tb, Whi, bhi, (float*)d_out, kM, kE, kR);
  }
}

// Round 3
// 526.410 us; speedup vs baseline: 3.3205x; 1.4514x over previous
//
#include <hip/hip_runtime.h>

namespace {

constexpr int kE  = 1024;
constexpr int kH  = 16;
constexpr int kR  = 256;
constexpr int kHD = 64;
constexpr int kB  = 2;
constexpr int kS  = 2048;
constexpr int kM  = kB * kS;   // 4096

typedef float  floatx4 __attribute__((ext_vector_type(4)));
typedef short  short8  __attribute__((ext_vector_type(8)));
typedef short  short4  __attribute__((ext_vector_type(4)));

__device__ inline short f2bf(float f) {
  union { float f; unsigned u; } x{f};
  unsigned r = x.u + 0x7FFF + ((x.u >> 16) & 1);   // RNE
  return (short)(r >> 16);
}

// async global->LDS, 16B per lane. LDS dest = wave-uniform base + lane*16.
__device__ inline void async_copy16(const void* g, void* l) {
  __builtin_amdgcn_global_load_lds(
      (const __attribute__((address_space(1))) unsigned int*)g,
      (__attribute__((address_space(3))) unsigned int*)l,
      16, 0, 0);
}

#if __has_builtin(__builtin_amdgcn_mfma_f32_16x16x16bf16_1k)
  #define MFMA16(a, b, c) __builtin_amdgcn_mfma_f32_16x16x16bf16_1k(a, b, c, 0, 0, 0)
  #define HAVE_MFMA_K16 1
#elif __has_builtin(__builtin_amdgcn_mfma_f32_16x16x16_bf16)
  #define MFMA16(a, b, c) __builtin_amdgcn_mfma_f32_16x16x16_bf16(a, b, c, 0, 0, 0)
  #define HAVE_MFMA_K16 1
#else
  #define HAVE_MFMA_K16 0
#endif

// ---------------------------------------------------------------------------
// Weight prep: fp32 W (K,N) row-major -> bf16 W^T (N,K) row-major.
// 8 matrices; even ids are _lo (1024x256), odd are _hi (256x1024).
// ---------------------------------------------------------------------------
struct PrepArgs { const float* src[8]; short* dst[8]; };

__global__ __launch_bounds__(256) void prep_weights(PrepArgs pa) {
  const int id = blockIdx.y;
  const bool lo = (id & 1) == 0;
  const int K = lo ? 1024 : 256;
  const int N = lo ? 256 : 1024;
  const int tiles_k = K >> 6;
  const int k0 = (blockIdx.x % tiles_k) * 64;
  const int n0 = (blockIdx.x / tiles_k) * 64;
  const float* src = pa.src[id];
  short* dst = pa.dst[id];

  __shared__ float tile[64][68];
  const int t  = threadIdx.x;
  const int c4 = (t & 15) * 4;
  const int r  = t >> 4;

#pragma unroll
  for (int i = 0; i < 4; ++i) {
    const int rk = r + i * 16;
    *(float4*)&tile[rk][c4] = *(const float4*)&src[(size_t)(k0 + rk) * N + n0 + c4];
  }
  __syncthreads();
#pragma unroll
  for (int i = 0; i < 4; ++i) {
    const int rn = r + i * 16;
    short4 o = { f2bf(tile[c4 + 0][rn]), f2bf(tile[c4 + 1][rn]),
                 f2bf(tile[c4 + 2][rn]), f2bf(tile[c4 + 3][rn]) };
    *(short4*)&dst[(size_t)(n0 + rn) * K + k0 + c4] = o;
  }
}

// ---------------------------------------------------------------------------
// q/k/v fp32 -> bf16 row-major. 8 elements per thread.
// ---------------------------------------------------------------------------
__global__ __launch_bounds__(256) void convert_in(
    const float* q, const float* k, const float* v,
    short* xq, short* xk, short* xv)
{
  const float* srcs[3] = {q, k, v};
  short* dsts[3] = {xq, xk, xv};
  const float* s = srcs[blockIdx.y];
  short* d = dsts[blockIdx.y];
  const size_t i = ((size_t)blockIdx.x * 256 + threadIdx.x) * 8;
  float4 a = *(const float4*)(s + i);
  float4 b = *(const float4*)(s + i + 4);
  short8 o = { f2bf(a.x), f2bf(a.y), f2bf(a.z), f2bf(a.w),
               f2bf(b.x), f2bf(b.y), f2bf(b.z), f2bf(b.w) };
  *(short8*)(d + i) = o;
}

// ---------------------------------------------------------------------------
// bf16 MFMA GEMM, NT form: C[M,N] = A[M,K] @ Bt[N,K]^T + bias, M=4096.
// 256 thr = 4 waves (2x2), BK=32, global_load_lds 16B staging.
// MODE: 0 = bf16 out; 1 = bf16 out, z==2 writes V transposed (B*H,64,S);
//       2 = fp32 out.
// ---------------------------------------------------------------------------
struct GemmArgs {
  const short* A[3]; const short* Bt[3]; const float* bias[3];
  void* C[3]; float scale[3];
};

template <int N, int K, int BM, int BN, int MODE>
__global__ __launch_bounds__(256) void gemm_bf16(GemmArgs args) {
  constexpr int TILES_N = N / BN;
  constexpr int WTM = BM / 2, WTN = BN / 2;
  constexpr int FI = WTM / 16, FJ = WTN / 16;
  constexpr int AROUNDS = (BM * 64) / 4096;
  constexpr int BROUNDS = (BN * 64) / 4096;

  const int z = blockIdx.y;
  const int row0 = (blockIdx.x / TILES_N) * BM;
  const int col0 = (blockIdx.x % TILES_N) * BN;
  const short* A  = args.A[z];
  const short* Bt = args.Bt[z];
  const float* bias = args.bias[z];
  const float scale = args.scale[z];

  __shared__ short As[BM * 32];
  __shared__ short Bs[BN * 32];

  const int t    = threadIdx.x;
  const int wave = t >> 6;
  const int lane = t & 63;
  const int lq   = lane & 15;
  const int quad = lane >> 4;
  const int wm0  = (wave >> 1) * WTM;
  const int wn0  = (wave & 1) * WTN;

  const int srow = t >> 2;          // staging row within a round
  const int scol = (t & 3) * 8;     // staging k-offset (8 bf16 = 16B)

  floatx4 acc[FI][FJ] = {};

  for (int kk = 0; kk < K; kk += 32) {
#pragma unroll
    for (int r = 0; r < AROUNDS; ++r)
      async_copy16(A + (size_t)(row0 + r * 64 + srow) * K + kk + scol,
                   (char*)As + r * 4096 + wave * 1024);
#pragma unroll
    for (int r = 0; r < BROUNDS; ++r)
      async_copy16(Bt + (size_t)(col0 + r * 64 + srow) * K + kk + scol,
                   (char*)Bs + r * 4096 + wave * 1024);
    __syncthreads();

    short8 af[FI], bf[FJ];
#pragma unroll
    for (int i = 0; i < FI; ++i)
      af[i] = *(const short8*)((const char*)As + ((wm0 + i * 16 + lq) * 64 + quad * 16));
#pragma unroll
    for (int j = 0; j < FJ; ++j)
      bf[j] = *(const short8*)((const char*)Bs + ((wn0 + j * 16 + lq) * 64 + quad * 16));
#pragma unroll
    for (int i = 0; i < FI; ++i)
#pragma unroll
      for (int j = 0; j < FJ; ++j)
        acc[i][j] = __builtin_amdgcn_mfma_f32_16x16x32_bf16(af[i], bf[j], acc[i][j], 0, 0, 0);
    __syncthreads();
  }

#pragma unroll
  for (int i = 0; i < FI; ++i) {
    const int rbase = row0 + wm0 + i * 16 + quad * 4;
#pragma unroll
    for (int j = 0; j < FJ; ++j) {
      const int col = col0 + wn0 + j * 16 + lq;
      const float bj = bias[col];
      if (MODE == 2) {
        float* C = (float*)args.C[z];
#pragma unroll
        for (int r = 0; r < 4; ++r)
          C[(size_t)(rbase + r) * N + col] = (acc[i][j][r] + bj) * scale;
      } else if (MODE == 1 && z == 2) {
        // V transposed: Vt[(b*16+h)*64 + d][s], s = 4 consecutive rows
        short* C = (short*)args.C[z];
        const int h = col >> 6, d = col & 63;
        const int b = rbase >> 11;
        const int s = rbase & 2047;
        short4 o = { f2bf(acc[i][j][0] + bj), f2bf(acc[i][j][1] + bj),
                     f2bf(acc[i][j][2] + bj), f2bf(acc[i][j][3] + bj) };
        *(short4*)&C[((size_t)((b * 16 + h) * 64 + d)) * 2048 + s] = o;
      } else {
        short* C = (short*)args.C[z];
#pragma unroll
        for (int r = 0; r < 4; ++r)
          C[(size_t)(rbase + r) * N + col] = f2bf((acc[i][j][r] + bj) * scale);
      }
    }
  }
}

// ---------------------------------------------------------------------------
// Flash attention, bf16 MFMA, 1 wave per block, 16 q-rows per wave.
// S^T = K @ Q^T (16x16x32). P stays in registers: the S^T C-layout
// (key=quad*4+r) IS the 16x16x16 B-operand layout (k=quad*4+j), so
// PV: O^T += V^T @ P^T runs with zero cross-lane movement and zero LDS.
// ---------------------------------------------------------------------------
__global__ __launch_bounds__(64, 4) void attn_mfma(
    const short* __restrict__ Qh, const short* __restrict__ Kh,
    const short* __restrict__ Vt, short* __restrict__ O)
{
  const int lane = threadIdx.x;
  const int lq   = lane & 15;
  const int quad = lane >> 4;

  const int q0 = blockIdx.x * 16;
  const int bh = blockIdx.y;
  const int b  = bh >> 4;
  const int h  = bh & 15;

  const short* qrow = Qh + ((size_t)(b * kS + q0 + lq)) * kE + h * kHD;
  short8 qf0 = *(const short8*)(qrow + quad * 8);
  short8 qf1 = *(const short8*)(qrow + 32 + quad * 8);

  const short* Kbase = Kh + (size_t)b * kS * kE + h * kHD;
  const short* Vbase = Vt + (size_t)bh * kHD * kS;

  floatx4 Oacc[4] = {};
  float m = -1e30f;
  float l = 0.f;

#if !HAVE_MFMA_K16
  __shared__ short Pbuf[16][72];
#endif

#pragma unroll 2
  for (int kc = 0; kc < kS; kc += 64) {
    // ---- V fragments first (longest dead time before use) ----
#if HAVE_MFMA_K16
    short4 vf[4][4];
#pragma unroll
    for (int dt = 0; dt < 4; ++dt) {
      const short* vrow = Vbase + ((size_t)(dt * 16 + lq)) * kS + kc;
#pragma unroll
      for (int tt = 0; tt < 4; ++tt)
        vf[dt][tt] = *(const short4*)(vrow + tt * 16 + quad * 4);
    }
#else
    short8 vf32[4][2];
#pragma unroll
    for (int dt = 0; dt < 4; ++dt) {
      const short* vrow = Vbase + ((size_t)(dt * 16 + lq)) * kS + kc;
      vf32[dt][0] = *(const short8*)(vrow + quad * 8);
      vf32[dt][1] = *(const short8*)(vrow + 32 + quad * 8);
    }
#endif

    // ---- scores: S^T tiles (key16 x q16) ----
    floatx4 Sc[4];
#pragma unroll
    for (int tt = 0; tt < 4; ++tt) {
      const short* krow = Kbase + ((size_t)(kc + tt * 16 + lq)) * kE;
      short8 a0 = *(const short8*)(krow + quad * 8);
      short8 a1 = *(const short8*)(krow + 32 + quad * 8);
      floatx4 c = {};
      c = __builtin_amdgcn_mfma_f32_16x16x32_bf16(a0, qf0, c, 0, 0, 0);
      c = __builtin_amdgcn_mfma_f32_16x16x32_bf16(a1, qf1, c, 0, 0, 0);
      Sc[tt] = c;
    }

    // ---- online softmax ----
    float mc = -1e30f;
#pragma unroll
    for (int tt = 0; tt < 4; ++tt)
#pragma unroll
      for (int r = 0; r < 4; ++r) mc = fmaxf(mc, Sc[tt][r]);
    mc = fmaxf(mc, __shfl_xor(mc, 16, 64));
    mc = fmaxf(mc, __shfl_xor(mc, 32, 64));
    const float mn = fmaxf(m, mc);
    const float alpha = __expf(m - mn);
    m = mn;

    float ls = 0.f;
#if HAVE_MFMA_K16
    short4 pf[4];
#pragma unroll
    for (int tt = 0; tt < 4; ++tt) {
      float p0 = __expf(Sc[tt][0] - m);
      float p1 = __expf(Sc[tt][1] - m);
      float p2 = __expf(Sc[tt][2] - m);
      float p3 = __expf(Sc[tt][3] - m);
      ls += (p0 + p1) + (p2 + p3);
      pf[tt] = short4{ f2bf(p0), f2bf(p1), f2bf(p2), f2bf(p3) };
    }
#else
#pragma unroll
    for (int tt = 0; tt < 4; ++tt) {
      float p0 = __expf(Sc[tt][0] - m);
      float p1 = __expf(Sc[tt][1] - m);
      float p2 = __expf(Sc[tt][2] - m);
      float p3 = __expf(Sc[tt][3] - m);
      ls += (p0 + p1) + (p2 + p3);
      short4 pk = { f2bf(p0), f2bf(p1), f2bf(p2), f2bf(p3) };
      *(short4*)&Pbuf[lq][tt * 16 + quad * 4] = pk;
    }
#endif
    l = l * alpha + ls;
#pragma unroll
    for (int dt = 0; dt < 4; ++dt)
#pragma unroll
      for (int r = 0; r < 4; ++r) Oacc[dt][r] *= alpha;

    // ---- PV ----
#if HAVE_MFMA_K16
#pragma unroll
    for (int dt = 0; dt < 4; ++dt)
#pragma unroll
      for (int tt = 0; tt < 4; ++tt)
        Oacc[dt] = MFMA16(vf[dt][tt], pf[tt], Oacc[dt]);
#else
    asm volatile("s_waitcnt lgkmcnt(0)" ::: "memory");
    short8 pb0 = *(const short8*)&Pbuf[lq][quad * 8];
    short8 pb1 = *(const short8*)&Pbuf[lq][32 + quad * 8];
#pragma unroll
    for (int dt = 0; dt < 4; ++dt) {
      Oacc[dt] = __builtin_amdgcn_mfma_f32_16x16x32_bf16(vf32[dt][0], pb0, Oacc[dt], 0, 0, 0);
      Oacc[dt] = __builtin_amdgcn_mfma_f32_16x16x32_bf16(vf32[dt][1], pb1, Oacc[dt], 0, 0, 0);
    }
    asm volatile("s_waitcnt lgkmcnt(0)" ::: "memory");
#endif
  }

  // ---- epilogue ----
  l += __shfl_xor(l, 16, 64);
  l += __shfl_xor(l, 32, 64);
  const float inv = 1.f / l;

  short* orow = O + ((size_t)(b * kS + q0 + lq)) * kE + h * kHD;
#pragma unroll
  for (int dt = 0; dt < 4; ++dt) {
    short4 o = { f2bf(Oacc[dt][0] * inv), f2bf(Oacc[dt][1] * inv),
                 f2bf(Oacc[dt][2] * inv), f2bf(Oacc[dt][3] * inv) };
    *(short4*)&orow[dt * 16 + quad * 4] = o;
  }
}

}  // namespace

extern "C" void kernel_launch(void* const* d_in, const int* in_sizes, int n_in,
                              void* d_out, int out_size, void* d_ws, size_t ws_size,
                              hipStream_t stream) {
  // ---- workspace layout (bf16 shorts) ----
  short* ws = (short*)d_ws;
  short* Xq  = ws;                         // 4M
  short* Xk  = Xq  + (size_t)kM * kE;
  short* Xv  = Xk  + (size_t)kM * kE;
  short* Tq  = Xv  + (size_t)kM * kE;      // 1M each
  short* Tk  = Tq  + (size_t)kM * kR;
  short* Tv  = Tk  + (size_t)kM * kR;
  short* Qh  = Tv  + (size_t)kM * kR;      // 4M each
  short* Kh  = Qh  + (size_t)kM * kE;
  short* Vth = Kh  + (size_t)kM * kE;      // (B*H, 64, S)
  short* Ab  = Vth + (size_t)kM * kE;      // attn out bf16
  short* To  = Ab  + (size_t)kM * kE;      // 1M
  short* Wt  = To  + (size_t)kM * kR;      // 8 x 256K

  short* WtArr[8];
  for (int i = 0; i < 8; ++i) WtArr[i] = Wt + (size_t)i * (kE * kR);

  // ---- 1. weight transpose+convert ----
  PrepArgs pa;
  const int widx[8] = {3, 5, 7, 9, 11, 13, 15, 17};
  for (int i = 0; i < 8; ++i) { pa.src[i] = (const float*)d_in[widx[i]]; pa.dst[i] = WtArr[i]; }
  prep_weights<<<dim3(64, 8), dim3(256), 0, stream>>>(pa);

  // ---- 2. input convert ----
  convert_in<<<dim3((kM * kE) / (256 * 8), 3), dim3(256), 0, stream>>>(
      (const float*)d_in[0], (const float*)d_in[1], (const float*)d_in[2], Xq, Xk, Xv);

  // ---- 3. qkv lo GEMMs (batched z=0..2): X @ Wlo + blo -> T ----
  {
    GemmArgs ga;
    ga.A[0] = Xq; ga.A[1] = Xk; ga.A[2] = Xv;
    ga.Bt[0] = WtArr[0]; ga.Bt[1] = WtArr[2]; ga.Bt[2] = WtArr[4];
    ga.bias[0] = (const float*)d_in[4]; ga.bias[1] = (const float*)d_in[8]; ga.bias[2] = (const float*)d_in[12];
    ga.C[0] = Tq; ga.C[1] = Tk; ga.C[2] = Tv;
    ga.scale[0] = ga.scale[1] = ga.scale[2] = 1.f;
    gemm_bf16<kR, kE, 64, 64, 0><<<dim3((kM / 64) * (kR / 64), 3), dim3(256), 0, stream>>>(ga);
  }

  // ---- 4. qkv hi GEMMs: T @ Whi + bhi -> Qh (x0.125), Kh, Vth (transposed) ----
  {
    GemmArgs ga;
    ga.A[0] = Tq; ga.A[1] = Tk; ga.A[2] = Tv;
    ga.Bt[0] = WtArr[1]; ga.Bt[1] = WtArr[3]; ga.Bt[2] = WtArr[5];
    ga.bias[0] = (const float*)d_in[6]; ga.bias[1] = (const float*)d_in[10]; ga.bias[2] = (const float*)d_in[14];
    ga.C[0] = Qh; ga.C[1] = Kh; ga.C[2] = Vth;
    ga.scale[0] = 0.125f; ga.scale[1] = 1.f; ga.scale[2] = 1.f;
    gemm_bf16<kE, kR, 128, 128, 1><<<dim3((kM / 128) * (kE / 128), 3), dim3(256), 0, stream>>>(ga);
  }

  // ---- 5. attention ----
  attn_mfma<<<dim3(kS / 16, kB * kH), dim3(64), 0, stream>>>(Qh, Kh, Vth, Ab);

  // ---- 6. output projection ----
  {
    GemmArgs ga;
    ga.A[0] = Ab; ga.Bt[0] = WtArr[6];
    ga.bias[0] = (const float*)d_in[16];
    ga.C[0] = To; ga.scale[0] = 1.f;
    gemm_bf16<kR, kE, 64, 64, 0><<<dim3((kM / 64) * (kR / 64), 1), dim3(256), 0, stream>>>(ga);
  }
  {
    GemmArgs ga;
    ga.A[0] = To; ga.Bt[0] = WtArr[7];
    ga.bias[0] = (const float*)d_in[18];
    ga.C[0] = d_out; ga.scale[0] = 1.f;
    gemm_bf16<kE, kR, 128, 128, 2><<<dim3((kM / 128) * (kE / 128), 1), dim3(256), 0, stream>>>(ga);
  }
}

// Round 5
// 261.856 us; speedup vs baseline: 6.6751x; 2.0103x over previous
//
#include <hip/hip_runtime.h>

namespace {

constexpr int kE  = 1024;
constexpr int kH  = 16;
constexpr int kR  = 256;
constexpr int kHD = 64;
constexpr int kB  = 2;
constexpr int kS  = 2048;
constexpr int kM  = kB * kS;   // 4096

typedef float  floatx4 __attribute__((ext_vector_type(4)));
typedef short  short8  __attribute__((ext_vector_type(8)));
typedef short  short4  __attribute__((ext_vector_type(4)));

__device__ inline short f2bf(float f) {
  union { float f; unsigned u; } x{f};
  unsigned r = x.u + 0x7FFF + ((x.u >> 16) & 1);   // RNE
  return (short)(r >> 16);
}

// async global->LDS, 16B per lane. LDS dest = wave-uniform base + lane*16.
__device__ inline void async_copy16(const void* g, void* l) {
  __builtin_amdgcn_global_load_lds(
      (const __attribute__((address_space(1))) unsigned int*)g,
      (__attribute__((address_space(3))) unsigned int*)l,
      16, 0, 0);
}

// 16x16x16 bf16 MFMA (A/B = 4 bf16 in 2 VGPRs). __has_builtin is FALSE on the
// host pass of the HIP TU -> must guard with __HIP_DEVICE_COMPILE__ and give
// the host a parse-only stub (device pass verified working in round 3).
#if defined(__HIP_DEVICE_COMPILE__)
  #if __has_builtin(__builtin_amdgcn_mfma_f32_16x16x16bf16_1k)
    #define MFMA16(a, b, c) __builtin_amdgcn_mfma_f32_16x16x16bf16_1k(a, b, c, 0, 0, 0)
  #elif __has_builtin(__builtin_amdgcn_mfma_f32_16x16x16_bf16)
    #define MFMA16(a, b, c) __builtin_amdgcn_mfma_f32_16x16x16_bf16(a, b, c, 0, 0, 0)
  #else
    #error "no 16x16x16 bf16 MFMA builtin on device"
  #endif
#else
  #define MFMA16(a, b, c) (c)   // host pass: never executed
#endif

// ---------------------------------------------------------------------------
// Weight prep: fp32 W (K,N) row-major -> bf16 W^T (N,K) row-major.
// ---------------------------------------------------------------------------
struct PrepArgs { const float* src[8]; short* dst[8]; };

__global__ __launch_bounds__(256) void prep_weights(PrepArgs pa) {
  const int id = blockIdx.y;
  const bool lo = (id & 1) == 0;
  const int K = lo ? 1024 : 256;
  const int N = lo ? 256 : 1024;
  const int tiles_k = K >> 6;
  const int k0 = (blockIdx.x % tiles_k) * 64;
  const int n0 = (blockIdx.x / tiles_k) * 64;
  const float* src = pa.src[id];
  short* dst = pa.dst[id];

  __shared__ float tile[64][68];
  const int t  = threadIdx.x;
  const int c4 = (t & 15) * 4;
  const int r  = t >> 4;

#pragma unroll
  for (int i = 0; i < 4; ++i) {
    const int rk = r + i * 16;
    *(float4*)&tile[rk][c4] = *(const float4*)&src[(size_t)(k0 + rk) * N + n0 + c4];
  }
  __syncthreads();
#pragma unroll
  for (int i = 0; i < 4; ++i) {
    const int rn = r + i * 16;
    short4 o = { f2bf(tile[c4 + 0][rn]), f2bf(tile[c4 + 1][rn]),
                 f2bf(tile[c4 + 2][rn]), f2bf(tile[c4 + 3][rn]) };
    *(short4*)&dst[(size_t)(n0 + rn) * K + k0 + c4] = o;
  }
}

// ---------------------------------------------------------------------------
// q/k/v fp32 -> bf16 row-major. 8 elements per thread.
// ---------------------------------------------------------------------------
__global__ __launch_bounds__(256) void convert_in(
    const float* q, const float* k, const float* v,
    short* xq, short* xk, short* xv)
{
  const float* srcs[3] = {q, k, v};
  short* dsts[3] = {xq, xk, xv};
  const float* s = srcs[blockIdx.y];
  short* d = dsts[blockIdx.y];
  const size_t i = ((size_t)blockIdx.x * 256 + threadIdx.x) * 8;
  float4 a = *(const float4*)(s + i);
  float4 b = *(const float4*)(s + i + 4);
  short8 o = { f2bf(a.x), f2bf(a.y), f2bf(a.z), f2bf(a.w),
               f2bf(b.x), f2bf(b.y), f2bf(b.z), f2bf(b.w) };
  *(short8*)(d + i) = o;
}

// ---------------------------------------------------------------------------
// bf16 MFMA GEMM, NT form: C[M,N] = A[M,K] @ Bt[N,K]^T + bias, M=4096.
// MODE 0: bf16 row-major out.
// MODE 1: bf16 out in attention layouts: z<2 -> head-major (b*H+h, s, d);
//         z==2 -> head-major transposed (b*H+h, d, s).
// MODE 2: fp32 row-major out.
// ---------------------------------------------------------------------------
struct GemmArgs {
  const short* A[3]; const short* Bt[3]; const float* bias[3];
  void* C[3]; float scale[3];
};

template <int N, int K, int BM, int BN, int MODE>
__global__ __launch_bounds__(256) void gemm_bf16(GemmArgs args) {
  constexpr int TILES_N = N / BN;
  constexpr int WTM = BM / 2, WTN = BN / 2;
  constexpr int FI = WTM / 16, FJ = WTN / 16;
  constexpr int AROUNDS = (BM * 64) / 4096;
  constexpr int BROUNDS = (BN * 64) / 4096;

  const int z = blockIdx.y;
  const int row0 = (blockIdx.x / TILES_N) * BM;
  const int col0 = (blockIdx.x % TILES_N) * BN;
  const short* A  = args.A[z];
  const short* Bt = args.Bt[z];
  const float* bias = args.bias[z];
  const float scale = args.scale[z];

  __shared__ short As[BM * 32];
  __shared__ short Bs[BN * 32];

  const int t    = threadIdx.x;
  const int wave = t >> 6;
  const int lane = t & 63;
  const int lq   = lane & 15;
  const int quad = lane >> 4;
  const int wm0  = (wave >> 1) * WTM;
  const int wn0  = (wave & 1) * WTN;

  const int srow = t >> 2;
  const int scol = (t & 3) * 8;

  floatx4 acc[FI][FJ] = {};

  for (int kk = 0; kk < K; kk += 32) {
#pragma unroll
    for (int r = 0; r < AROUNDS; ++r)
      async_copy16(A + (size_t)(row0 + r * 64 + srow) * K + kk + scol,
                   (char*)As + r * 4096 + wave * 1024);
#pragma unroll
    for (int r = 0; r < BROUNDS; ++r)
      async_copy16(Bt + (size_t)(col0 + r * 64 + srow) * K + kk + scol,
                   (char*)Bs + r * 4096 + wave * 1024);
    __syncthreads();

    short8 af[FI], bf[FJ];
#pragma unroll
    for (int i = 0; i < FI; ++i)
      af[i] = *(const short8*)((const char*)As + ((wm0 + i * 16 + lq) * 64 + quad * 16));
#pragma unroll
    for (int j = 0; j < FJ; ++j)
      bf[j] = *(const short8*)((const char*)Bs + ((wn0 + j * 16 + lq) * 64 + quad * 16));
#pragma unroll
    for (int i = 0; i < FI; ++i)
#pragma unroll
      for (int j = 0; j < FJ; ++j)
        acc[i][j] = __builtin_amdgcn_mfma_f32_16x16x32_bf16(af[i], bf[j], acc[i][j], 0, 0, 0);
    __syncthreads();
  }

#pragma unroll
  for (int i = 0; i < FI; ++i) {
    const int rbase = row0 + wm0 + i * 16 + quad * 4;
#pragma unroll
    for (int j = 0; j < FJ; ++j) {
      const int col = col0 + wn0 + j * 16 + lq;
      const float bj = bias[col];
      if (MODE == 2) {
        float* C = (float*)args.C[z];
#pragma unroll
        for (int r = 0; r < 4; ++r)
          C[(size_t)(rbase + r) * N + col] = (acc[i][j][r] + bj) * scale;
      } else if (MODE == 1) {
        short* C = (short*)args.C[z];
        const int h = col >> 6, d = col & 63;
        const int b = rbase >> 11, s = rbase & 2047;
        if (z == 2) {
          // V^T head-major: (bh, d, s); 4 consecutive s
          short4 o = { f2bf(acc[i][j][0] + bj), f2bf(acc[i][j][1] + bj),
                       f2bf(acc[i][j][2] + bj), f2bf(acc[i][j][3] + bj) };
          *(short4*)&C[((size_t)((b * 16 + h) * 64 + d)) * 2048 + s] = o;
        } else {
          // Q/K head-major: (bh, s, d)
#pragma unroll
          for (int r = 0; r < 4; ++r)
            C[((size_t)((b * 16 + h) * 2048 + s + r)) * 64 + d] =
                f2bf((acc[i][j][r] + bj) * scale);
        }
      } else {
        short* C = (short*)args.C[z];
#pragma unroll
        for (int r = 0; r < 4; ++r)
          C[(size_t)(rbase + r) * N + col] = f2bf((acc[i][j][r] + bj) * scale);
      }
    }
  }
}

// ---------------------------------------------------------------------------
// Flash attention, bf16 MFMA. Block = 4 waves, 64 q-rows (16/wave).
// Per 64-key chunk: K (64x64) and V^T (64x64) staged ONCE into padded LDS by
// coalesced cooperative loads; all 4 waves read fragments from LDS.
// S^T = K @ Q^T (16x16x32, A from LDS); P stays in registers (S^T C-layout ==
// 16x16x16 B-layout); O^T += V^T @ P^T (A from LDS, 16x16x16).
// Next chunk's staging registers prefetched right after the barrier.
// ---------------------------------------------------------------------------
__global__ __launch_bounds__(256) void attn_mfma(
    const short* __restrict__ Qp, const short* __restrict__ Kp,
    const short* __restrict__ Vtp, short* __restrict__ O)
{
  __shared__ short Ks[64][72];   // [local key][d], pad 72 (144B rows, 16B-aligned)
  __shared__ short Vs[64][72];   // [d][local key]

  const int t    = threadIdx.x;
  const int wave = t >> 6;
  const int lane = t & 63;
  const int lq   = lane & 15;
  const int quad = lane >> 4;

  const int q0 = blockIdx.x * 64;
  const int bh = blockIdx.y;
  const int b  = bh >> 4;
  const int h  = bh & 15;

  // Q fragments (head-major (bh,s,d)): n=q=lq, k=d
  const short* qrow = Qp + ((size_t)bh * kS + q0 + wave * 16 + lq) * 64;
  short8 qf0 = *(const short8*)(qrow + quad * 8);
  short8 qf1 = *(const short8*)(qrow + 32 + quad * 8);

  const short* Kbase = Kp  + (size_t)bh * kS * 64;   // (s, d) rows of 128B
  const short* Vbase = Vtp + (size_t)bh * 64 * kS;   // (d, s) rows of 4KB

  // staging: wave w covers rows w*16 .. w*16+15 via two 8-row coalesced loads
  const int srow = wave * 16 + (lane >> 3);
  const int scol = (lane & 7) * 8;

  floatx4 Oacc[4] = {};
  float m = -1e30f;
  float l = 0.f;

  short8 gk0 = *(const short8*)(Kbase + (size_t)(srow) * 64 + scol);
  short8 gk1 = *(const short8*)(Kbase + (size_t)(srow + 8) * 64 + scol);
  short8 gv0 = *(const short8*)(Vbase + (size_t)srow * kS + scol);
  short8 gv1 = *(const short8*)(Vbase + (size_t)(srow + 8) * kS + scol);

  for (int kc = 0; kc < kS; kc += 64) {
    __syncthreads();                      // previous chunk's reads done
    *(short8*)&Ks[srow][scol]     = gk0;
    *(short8*)&Ks[srow + 8][scol] = gk1;
    *(short8*)&Vs[srow][scol]     = gv0;
    *(short8*)&Vs[srow + 8][scol] = gv1;
    __syncthreads();                      // tiles visible

    if (kc + 64 < kS) {                   // prefetch next chunk (hidden by compute)
      gk0 = *(const short8*)(Kbase + (size_t)(kc + 64 + srow) * 64 + scol);
      gk1 = *(const short8*)(Kbase + (size_t)(kc + 64 + srow + 8) * 64 + scol);
      gv0 = *(const short8*)(Vbase + (size_t)srow * kS + kc + 64 + scol);
      gv1 = *(const short8*)(Vbase + (size_t)(srow + 8) * kS + kc + 64 + scol);
    }

    // ---- scores: S^T tiles (key16 x q16), A = K rows from LDS ----
    floatx4 Sc[4];
#pragma unroll
    for (int tt = 0; tt < 4; ++tt) {
      short8 a0 = *(const short8*)&Ks[tt * 16 + lq][quad * 8];
      short8 a1 = *(const short8*)&Ks[tt * 16 + lq][32 + quad * 8];
      floatx4 c = {};
      c = __builtin_amdgcn_mfma_f32_16x16x32_bf16(a0, qf0, c, 0, 0, 0);
      c = __builtin_amdgcn_mfma_f32_16x16x32_bf16(a1, qf1, c, 0, 0, 0);
      Sc[tt] = c;
    }

    // ---- online softmax ----
    float mc = -1e30f;
#pragma unroll
    for (int tt = 0; tt < 4; ++tt)
#pragma unroll
      for (int r = 0; r < 4; ++r) mc = fmaxf(mc, Sc[tt][r]);
    mc = fmaxf(mc, __shfl_xor(mc, 16, 64));
    mc = fmaxf(mc, __shfl_xor(mc, 32, 64));
    const float mn = fmaxf(m, mc);
    const float alpha = __expf(m - mn);
    m = mn;

    float ls = 0.f;
    short4 pf[4];
#pragma unroll
    for (int tt = 0; tt < 4; ++tt) {
      float p0 = __expf(Sc[tt][0] - m);
      float p1 = __expf(Sc[tt][1] - m);
      float p2 = __expf(Sc[tt][2] - m);
      float p3 = __expf(Sc[tt][3] - m);
      ls += (p0 + p1) + (p2 + p3);
      pf[tt] = short4{ f2bf(p0), f2bf(p1), f2bf(p2), f2bf(p3) };
    }
    l = l * alpha + ls;
#pragma unroll
    for (int dt = 0; dt < 4; ++dt)
#pragma unroll
      for (int r = 0; r < 4; ++r) Oacc[dt][r] *= alpha;

    // ---- PV: O^T += V^T @ P^T, A = V^T rows from LDS ----
#pragma unroll
    for (int dt = 0; dt < 4; ++dt) {
#pragma unroll
      for (int tt = 0; tt < 4; ++tt) {
        short4 vf = *(const short4*)&Vs[dt * 16 + lq][tt * 16 + quad * 4];
        Oacc[dt] = MFMA16(vf, pf[tt], Oacc[dt]);
      }
    }
  }

  // ---- epilogue ----
  l += __shfl_xor(l, 16, 64);
  l += __shfl_xor(l, 32, 64);
  const float inv = 1.f / l;

  short* orow = O + ((size_t)(b * kS + q0 + wave * 16 + lq)) * kE + h * kHD;
#pragma unroll
  for (int dt = 0; dt < 4; ++dt) {
    short4 o = { f2bf(Oacc[dt][0] * inv), f2bf(Oacc[dt][1] * inv),
                 f2bf(Oacc[dt][2] * inv), f2bf(Oacc[dt][3] * inv) };
    *(short4*)&orow[dt * 16 + quad * 4] = o;
  }
}

}  // namespace

extern "C" void kernel_launch(void* const* d_in, const int* in_sizes, int n_in,
                              void* d_out, int out_size, void* d_ws, size_t ws_size,
                              hipStream_t stream) {
  // ---- workspace layout (bf16 shorts) ----
  short* ws = (short*)d_ws;
  short* Xq  = ws;                         // 4M
  short* Xk  = Xq  + (size_t)kM * kE;
  short* Xv  = Xk  + (size_t)kM * kE;
  short* Tq  = Xv  + (size_t)kM * kE;      // 1M each
  short* Tk  = Tq  + (size_t)kM * kR;
  short* Tv  = Tk  + (size_t)kM * kR;
  short* Qh  = Tv  + (size_t)kM * kR;      // 4M each; head-major layouts
  short* Kh  = Qh  + (size_t)kM * kE;
  short* Vth = Kh  + (size_t)kM * kE;      // (B*H, 64, S)
  short* Ab  = Vth + (size_t)kM * kE;      // attn out bf16 (b,s,E)
  short* To  = Ab  + (size_t)kM * kE;      // 1M
  short* Wt  = To  + (size_t)kM * kR;      // 8 x 256K

  short* WtArr[8];
  for (int i = 0; i < 8; ++i) WtArr[i] = Wt + (size_t)i * (kE * kR);

  // ---- 1. weight transpose+convert ----
  PrepArgs pa;
  const int widx[8] = {3, 5, 7, 9, 11, 13, 15, 17};
  for (int i = 0; i < 8; ++i) { pa.src[i] = (const float*)d_in[widx[i]]; pa.dst[i] = WtArr[i]; }
  prep_weights<<<dim3(64, 8), dim3(256), 0, stream>>>(pa);

  // ---- 2. input convert ----
  convert_in<<<dim3((kM * kE) / (256 * 8), 3), dim3(256), 0, stream>>>(
      (const float*)d_in[0], (const float*)d_in[1], (const float*)d_in[2], Xq, Xk, Xv);

  // ---- 3. qkv lo GEMMs ----
  {
    GemmArgs ga;
    ga.A[0] = Xq; ga.A[1] = Xk; ga.A[2] = Xv;
    ga.Bt[0] = WtArr[0]; ga.Bt[1] = WtArr[2]; ga.Bt[2] = WtArr[4];
    ga.bias[0] = (const float*)d_in[4]; ga.bias[1] = (const float*)d_in[8]; ga.bias[2] = (const float*)d_in[12];
    ga.C[0] = Tq; ga.C[1] = Tk; ga.C[2] = Tv;
    ga.scale[0] = ga.scale[1] = ga.scale[2] = 1.f;
    gemm_bf16<kR, kE, 64, 64, 0><<<dim3((kM / 64) * (kR / 64), 3), dim3(256), 0, stream>>>(ga);
  }

  // ---- 4. qkv hi GEMMs -> attention layouts ----
  {
    GemmArgs ga;
    ga.A[0] = Tq; ga.A[1] = Tk; ga.A[2] = Tv;
    ga.Bt[0] = WtArr[1]; ga.Bt[1] = WtArr[3]; ga.Bt[2] = WtArr[5];
    ga.bias[0] = (const float*)d_in[6]; ga.bias[1] = (const float*)d_in[10]; ga.bias[2] = (const float*)d_in[14];
    ga.C[0] = Qh; ga.C[1] = Kh; ga.C[2] = Vth;
    ga.scale[0] = 0.125f; ga.scale[1] = 1.f; ga.scale[2] = 1.f;
    gemm_bf16<kE, kR, 128, 128, 1><<<dim3((kM / 128) * (kE / 128), 3), dim3(256), 0, stream>>>(ga);
  }

  // ---- 5. attention ----
  attn_mfma<<<dim3(kS / 64, kB * kH), dim3(256), 0, stream>>>(Qh, Kh, Vth, Ab);

  // ---- 6. output projection ----
  {
    GemmArgs ga;
    ga.A[0] = Ab; ga.Bt[0] = WtArr[6];
    ga.bias[0] = (const float*)d_in[16];
    ga.C[0] = To; ga.scale[0] = 1.f;
    gemm_bf16<kR, kE, 64, 64, 0><<<dim3((kM / 64) * (kR / 64), 1), dim3(256), 0, stream>>>(ga);
  }
  {
    GemmArgs ga;
    ga.A[0] = To; ga.Bt[0] = WtArr[7];
    ga.bias[0] = (const float*)d_in[18];
    ga.C[0] = d_out; ga.scale[0] = 1.f;
    gemm_bf16<kE, kR, 128, 128, 2><<<dim3((kM / 128) * (kE / 128), 1), dim3(256), 0, stream>>>(ga);
  }
}